// Round 1
// baseline (568.755 us; speedup 1.0000x reference)
//
#include <hip/hip_runtime.h>

// One Gaussian per thread, but ALL global traffic vectorized to float4:
//  - rotation: float4 load (coalesced)
//  - features: single float4 load at 192B*n (16B-aligned; c0..c2 + 1 junk lane)
//  - scaling:  block-cooperative float4 load -> LDS, re-read per-thread
//  - cov3d/color: staged to LDS, cooperatively streamed out as contiguous float4
//  - cov2d: direct float4 store per thread (var,0,0,var)
//  - opacity: coalesced dword load/store
// LDS plan (floats): [0,768) scaling stage | [768,3072) cov3d | [3072,3840) color
// Regions disjoint -> only 2 barriers.

#define TPB 256

__global__ __launch_bounds__(TPB) void gauss_props_kernel(
    const float*  __restrict__ scaling_raw,   // (N,3)
    const float4* __restrict__ rotation,      // (N,4) as float4
    const float*  __restrict__ opacity_raw,   // (N,1)
    const float*  __restrict__ features,      // (N,16,3)
    float* __restrict__ out, int N)
{
    __shared__ float lds[3840];   // 15 KiB

    const int tid  = threadIdx.x;
    const int base = blockIdx.x * TPB;
    const int cnt  = min(TPB, N - base);
    const int n    = base + tid;
    const bool valid = tid < cnt;
    const bool full  = (cnt == TPB);
    const bool a16   = ((N & 3) == 0);   // float4 alignment of 9N / 13N regions

    // ---- Phase 0: cooperative scaling stage (768 floats = 192 float4) ----
    if (full) {
        if (tid < 192) {
            const float4* s4 = (const float4*)(scaling_raw + (size_t)3 * base); // 3072B*bid, aligned
            ((float4*)lds)[tid] = s4[tid];
        }
    } else {
        for (int i = tid; i < 3 * cnt; i += TPB)
            lds[i] = scaling_raw[(size_t)3 * base + i];
    }

    // per-thread direct loads overlap with the staging above
    float4 q = make_float4(0.f, 0.f, 0.f, 1.f);
    float  o = 0.f;
    float4 f = make_float4(0.f, 0.f, 0.f, 0.f);
    if (valid) {
        q = rotation[n];
        o = opacity_raw[n];
        f = *(const float4*)(features + (size_t)48 * n);  // 192B*n, 16B aligned
    }
    __syncthreads();

    float var = 0.f, opac = 0.f;
    if (valid) {
        const float s0 = __expf(2.f * lds[3 * tid + 0]);
        const float s1 = __expf(2.f * lds[3 * tid + 1]);
        const float s2 = __expf(2.f * lds[3 * tid + 2]);

        const float inv = rsqrtf(q.x * q.x + q.y * q.y + q.z * q.z + q.w * q.w);
        const float w = q.x * inv, x = q.y * inv, y = q.z * inv, z = q.w * inv;

        const float xx = x * x, yy = y * y, zz = z * z;
        const float wx = w * x, wy = w * y, wz = w * z;
        const float xy = x * y, xz = x * z, yz = y * z;

        float R[3][3];
        R[0][0] = 1.f - 2.f * (yy + zz); R[0][1] = 2.f * (xy - wz); R[0][2] = 2.f * (xz + wy);
        R[1][0] = 2.f * (xy + wz); R[1][1] = 1.f - 2.f * (xx + zz); R[1][2] = 2.f * (yz - wx);
        R[2][0] = 2.f * (xz - wy); R[2][1] = 2.f * (yz + wx); R[2][2] = 1.f - 2.f * (xx + yy);

        float trace = 0.f;
        #pragma unroll
        for (int i = 0; i < 3; ++i) {
            #pragma unroll
            for (int k = 0; k < 3; ++k) {
                const float c = R[i][0] * R[k][0] * s0
                              + R[i][1] * R[k][1] * s1
                              + R[i][2] * R[k][2] * s2;
                lds[768 + 9 * tid + 3 * i + k] = c;   // stride-9 dwords: 2-way bank alias = free
                if (i == k) trace += c;
            }
        }
        var  = trace * (1.f / 3.f);
        opac = 1.f / (1.f + __expf(-o));

        lds[3072 + 3 * tid + 0] = f.x;
        lds[3072 + 3 * tid + 1] = f.y;
        lds[3072 + 3 * tid + 2] = f.z;
    }
    __syncthreads();

    const size_t Ns = (size_t)N;

    // ---- cov2d: direct float4 per thread; opacity: coalesced dword ----
    if (valid) {
        if (a16) {
            ((float4*)(out + 9 * Ns))[n] = make_float4(var, 0.f, 0.f, var);
        } else {
            float* c2 = out + 9 * Ns + (size_t)4 * n;
            c2[0] = var; c2[1] = 0.f; c2[2] = 0.f; c2[3] = var;
        }
        out[16 * Ns + n] = opac;
    }

    // ---- cov3d: 2304 floats = 576 float4, contiguous stream ----
    {
        float* gdst = out + (size_t)9 * base;   // 9216B*bid, 16B aligned
        if (full) {
            float4*       d4 = (float4*)gdst;
            const float4* s4 = (const float4*)(lds + 768);
            d4[tid          ] = s4[tid          ];
            d4[tid + 1 * TPB] = s4[tid + 1 * TPB];
            if (tid < 64) d4[tid + 2 * TPB] = s4[tid + 2 * TPB];
        } else {
            for (int i = tid; i < 9 * cnt; i += TPB) gdst[i] = lds[768 + i];
        }
    }

    // ---- color: 768 floats = 192 float4, contiguous stream ----
    {
        float* gdst = out + 13 * Ns + (size_t)3 * base;
        if (full && a16) {
            float4*       d4 = (float4*)gdst;
            const float4* s4 = (const float4*)(lds + 3072);
            if (tid < 192) d4[tid] = s4[tid];
        } else {
            for (int i = tid; i < 3 * cnt; i += TPB) gdst[i] = lds[3072 + i];
        }
    }
}

extern "C" void kernel_launch(void* const* d_in, const int* in_sizes, int n_in,
                              void* d_out, int out_size, void* d_ws, size_t ws_size,
                              hipStream_t stream) {
    const float*  scaling  = (const float*)d_in[1];
    const float4* rotation = (const float4*)d_in[2];
    const float*  opacity  = (const float*)d_in[3];
    const float*  features = (const float*)d_in[4];
    float* out = (float*)d_out;

    int N = in_sizes[3]; // opacity_raw has N elements
    int threads = TPB;
    int blocks = (N + threads - 1) / threads;
    gauss_props_kernel<<<blocks, threads, 0, stream>>>(scaling, rotation, opacity,
                                                       features, out, N);
}